// Round 8
// baseline (551.756 us; speedup 1.0000x reference)
//
#include <hip/hip_runtime.h>

typedef unsigned short u16;
typedef __bf16 bf16x8 __attribute__((ext_vector_type(8)));
typedef float f32x4 __attribute__((ext_vector_type(4)));
typedef unsigned short u16x8 __attribute__((ext_vector_type(8)));

__device__ __forceinline__ float b2f(u16 b){ union{unsigned u; float f;} v; v.u=((unsigned)b)<<16; return v.f; }
__device__ __forceinline__ u16 f2b(float f){ unsigned u=__builtin_bit_cast(unsigned,f); return (u16)((u+0x7fffu+((u>>16)&1u))>>16); }
__device__ __forceinline__ float wred32(float v){
  #pragma unroll
  for(int off=16; off>0; off>>=1) v += __shfl_xor(v, off, 64);  // halves stay independent
  return v;
}
__device__ __forceinline__ bf16x8 cvt8(float4 lo, float4 hi){
  u16x8 t;
  t[0]=f2b(lo.x); t[1]=f2b(lo.y); t[2]=f2b(lo.z); t[3]=f2b(lo.w);
  t[4]=f2b(hi.x); t[5]=f2b(hi.y); t[6]=f2b(hi.z); t[7]=f2b(hi.w);
  return __builtin_bit_cast(bf16x8, t);
}

// ---------------- fused encoder: enc = relu(x@W1t^T + b1) @ W2t^T + b2 ----------------
// One block = 64 rows, 256 threads = 4 waves (4 col-groups). NO LDS staging of A or B:
//   - A-fragments loaded direct from global (fp32, line-coalesced, L1 dedups across waves)
//   - B-fragments (weights) loaded direct from L2/L3 (bf16, line-coalesced)
//   - h [64][320] lives ONLY in LDS (never in HBM), XOR-swizzled chunks [64][64]
// Zero barriers in the K-loops; 3 barriers total.
struct EP {
  const float* X[3];
  const u16*  W1[3];
  const float* B1[3];
  const u16*  W2[3];
  const float* B2[3];
  u16* E[3];
};

__global__ __launch_bounds__(256, 3) void enc_k(EP p)
{
  constexpr int CH = 4096;                 // [64][64] chunk (u16 elems)
  __shared__ __align__(16) u16 hs[5*CH];   // 40 KB
  const int z = blockIdx.z;
  const float* __restrict__ X   = p.X[z];
  const u16*   __restrict__ W1  = p.W1[z];
  const float* __restrict__ b1v = p.B1[z];
  const u16*   __restrict__ W2  = p.W2[z];
  const float* __restrict__ b2v = p.B2[z];
  u16* __restrict__ E = p.E[z];

  const int tid = threadIdx.x;
  const size_t m0 = (size_t)blockIdx.x * 64;
  const int lane = tid & 63, w = tid >> 6;
  const int lr = lane & 15, quad = lane >> 4;
  const int swz = (lr & 7) << 3;

  // ---- GEMM1: h = relu(x @ W1t^T + b1); x fp32 [64][256], W1t [320][256] ----
  const int wc1 = w * 80;                  // wave covers cols wc1..wc1+79 (5x16)
  f32x4 acc1[4][5];
  #pragma unroll
  for(int i=0;i<4;++i)
    #pragma unroll
    for(int j=0;j<5;++j) acc1[i][j] = (f32x4){0.f,0.f,0.f,0.f};

  const float* Xb = X + m0*256;
  for(int kk=0; kk<256; kk+=32){
    bf16x8 afr[4], bfr[5];
    #pragma unroll
    for(int i=0;i<4;++i){
      const float* s = Xb + (size_t)(i*16+lr)*256 + kk + quad*8;
      float4 lo = *(const float4*)s, hi = *(const float4*)(s+4);
      afr[i] = cvt8(lo, hi);
    }
    #pragma unroll
    for(int j=0;j<5;++j)
      bfr[j] = *(const bf16x8*)&W1[(size_t)(wc1+j*16+lr)*256 + kk + quad*8];
    #pragma unroll
    for(int i=0;i<4;++i)
      #pragma unroll
      for(int j=0;j<5;++j)
        acc1[i][j] = __builtin_amdgcn_mfma_f32_16x16x32_bf16(afr[i], bfr[j], acc1[i][j], 0, 0, 0);
  }
  // bias + relu + write h into swizzled LDS chunks (col>>6 = chunk, within = col&63)
  #pragma unroll
  for(int j=0;j<5;++j){
    int col = wc1 + j*16 + lr;
    float bv = (col < 300) ? b1v[col] : 0.f;
    int c = col >> 6, cwi = col & 63;
    #pragma unroll
    for(int i=0;i<4;++i)
      #pragma unroll
      for(int r=0;r<4;++r){
        int row = i*16 + quad*4 + r;
        float v = fmaxf(acc1[i][j][r] + bv, 0.f);
        hs[c*CH + row*64 + (cwi ^ ((row&7)<<3))] = f2b(v);
      }
  }
  __syncthreads();

  // ---- GEMM2: enc = h @ W2t^T + b2; K=320, W2t [256][320] ----
  const int wc2 = w * 64;
  f32x4 acc2[4][4];
  #pragma unroll
  for(int i=0;i<4;++i)
    #pragma unroll
    for(int j=0;j<4;++j) acc2[i][j] = (f32x4){0.f,0.f,0.f,0.f};

  for(int kkg=0; kkg<320; kkg+=32){
    const int c = kkg >> 6, kk = kkg & 63;
    bf16x8 afr[4], bfr[4];
    #pragma unroll
    for(int i=0;i<4;++i)
      afr[i] = *(const bf16x8*)&hs[c*CH + (i*16+lr)*64 + ((kk + quad*8) ^ swz)];
    #pragma unroll
    for(int j=0;j<4;++j)
      bfr[j] = *(const bf16x8*)&W2[(size_t)(wc2+j*16+lr)*320 + kkg + quad*8];
    #pragma unroll
    for(int i=0;i<4;++i)
      #pragma unroll
      for(int j=0;j<4;++j)
        acc2[i][j] = __builtin_amdgcn_mfma_f32_16x16x32_bf16(afr[i], bfr[j], acc2[i][j], 0, 0, 0);
  }
  __syncthreads();           // all h reads done; reuse hs as Ct [64][264]
  u16* Ct = hs;
  #pragma unroll
  for(int j=0;j<4;++j){
    int col = wc2 + j*16 + lr;
    float bv = b2v[col];
    #pragma unroll
    for(int i=0;i<4;++i)
      #pragma unroll
      for(int r=0;r<4;++r)
        Ct[(i*16 + quad*4 + r)*264 + col] = f2b(acc2[i][j][r] + bv);
  }
  __syncthreads();
  const int rowg = tid >> 2, cg = tid & 3;
  const size_t crow = (m0 + rowg)*256;
  #pragma unroll
  for(int k2=0; k2<8; ++k2){
    int cc = (cg + k2*4)*8;
    *(u16x8*)&E[crow + cc] = *(const u16x8*)&Ct[rowg*264 + cc];
  }
}

// ---------------- weight pre-transpose fp32->bf16 (+zero pad): dst[n*Kp+k] = src[k*N+n]
struct TPar { const float* src; u16* dst; int K, N, Kp, Np; };
struct TArgs { TPar p[8]; };
__global__ __launch_bounds__(256) void transpose_all(TArgs args){
  TPar p = args.p[blockIdx.y];
  int n = blockIdx.x;
  if (n >= p.Np) return;
  for (int k = threadIdx.x; k < p.Kp; k += 256){
    u16 v = 0;
    if (n < p.N && k < p.K) v = f2b(p.src[(size_t)k*p.N + n]);
    p.dst[(size_t)n*p.Kp + k] = v;
  }
}

// ---------------- fused tail: mid (norms/sims/gates) + gate GEMM + final GEMM ----------------
// One block = 64 rows. 512 threads = 8 waves (2 row-groups x 4 col-groups).
// LDS: cw 32KB + ww 32KB only (4 k-chunks [64][64] XOR-swizzled). B direct from L2.
// 3 barriers total; no staging.
__global__ __launch_bounds__(512, 4) void fuse3_k(
    const u16* __restrict__ eb, const u16* __restrict__ ef, const u16* __restrict__ ep,
    const float* __restrict__ Wg, const float* __restrict__ bg,
    const u16* __restrict__ WtE, const float* __restrict__ be,
    const u16* __restrict__ WtF, const float* __restrict__ bfv,
    float* __restrict__ out)
{
  __shared__ __align__(16) u16 cw[4*4096];
  __shared__ __align__(16) u16 ww[4*4096];

  const int tid = threadIdx.x;
  const size_t m0 = (size_t)blockIdx.x * 64;
  const int lane = tid & 63, w = tid >> 6;
  const int lr = lane & 15, quad = lane >> 4;
  const int wr = (w >> 2) * 32, wc = (w & 3) * 64;
  const int swz = (lr & 7) << 3;

  // ---- mid phase: 4 passes x 16 rows; 32 lanes x 8 elems per row ----
  const int rid = tid >> 5, l5 = tid & 31;
  for(int pass=0; pass<4; ++pass){
    int rloc = pass*16 + rid;
    size_t base = (m0 + rloc)*256 + l5*8;

    u16x8 vb = *(const u16x8*)(eb + base);
    u16x8 vf = *(const u16x8*)(ef + base);
    u16x8 vp = *(const u16x8*)(ep + base);
    float fb[8], ff[8], fp[8];
    #pragma unroll
    for(int j=0;j<8;++j){ fb[j]=b2f(vb[j]); ff[j]=b2f(vf[j]); fp[j]=b2f(vp[j]); }

    float sb=0, sf=0, sp=0, d01=0, d02=0, d12=0, g0=0, g1=0, g2=0;
    #pragma unroll
    for(int j=0;j<8;++j){
      sb += fb[j]*fb[j]; sf += ff[j]*ff[j]; sp += fp[j]*fp[j];
      d01 += fb[j]*ff[j]; d02 += fb[j]*fp[j]; d12 += ff[j]*fp[j];
    }
    #pragma unroll
    for(int seg=0; seg<3; ++seg){
      const float* x = (seg==0) ? fb : (seg==1) ? ff : fp;
      const float* wg = Wg + ((size_t)seg*256 + l5*8)*3;
      float wv[24];
      #pragma unroll
      for(int q=0;q<6;++q){
        float4 t = *(const float4*)(wg + q*4);
        wv[q*4+0]=t.x; wv[q*4+1]=t.y; wv[q*4+2]=t.z; wv[q*4+3]=t.w;
      }
      #pragma unroll
      for(int j=0;j<8;++j){
        g0 += x[j]*wv[j*3+0];
        g1 += x[j]*wv[j*3+1];
        g2 += x[j]*wv[j*3+2];
      }
    }
    sb=wred32(sb); sf=wred32(sf); sp=wred32(sp);
    d01=wred32(d01); d02=wred32(d02); d12=wred32(d12);
    g0=wred32(g0); g1=wred32(g1); g2=wred32(g2);

    float inb  = __builtin_amdgcn_rsqf(fmaxf(sb, 1e-24f));
    float invf = __builtin_amdgcn_rsqf(fmaxf(sf, 1e-24f));
    float inp  = __builtin_amdgcn_rsqf(fmaxf(sp, 1e-24f));
    float s01 = d01*inb*invf, s02 = d02*inb*inp, s12 = d12*invf*inp;

    float h0 = g0 + bg[0], h1 = g1 + bg[1], h2 = g2 + bg[2];
    float gm = fmaxf(h0, fmaxf(h1, h2));
    float e0 = __expf(h0-gm), e1 = __expf(h1-gm), e2 = __expf(h2-gm);
    float res = __builtin_amdgcn_rcpf(e0+e1+e2);
    float fw0 = e0*res, fw1 = e1*res, fw2 = e2*res;

    bool p0 = s01 > 0.6f, p1 = s02 > 0.6f, p2 = s12 > 0.6f;
    bool has = p0 || p1 || p2;
    float mm = -__builtin_inff();
    if(p0) mm = fmaxf(mm, s01);
    if(p1) mm = fmaxf(mm, s02);
    if(p2) mm = fmaxf(mm, s12);
    if(!has) mm = 0.f;
    float q0 = p0 ? __expf(s01-mm) : 0.f;
    float q1 = p1 ? __expf(s02-mm) : 0.f;
    float q2 = p2 ? __expf(s12-mm) : 0.f;
    float rqs = __builtin_amdgcn_rcpf(fmaxf(q0+q1+q2, 1e-12f));
    float w0 = q0*rqs, w1 = q1*rqs, w2 = q2*rqs;

    u16x8 oc, ow;
    #pragma unroll
    for(int j=0;j<8;++j){
      float a = fb[j], b = ff[j], c = fp[j];
      float na = a*inb, nbv = b*invf, nc = c*inp;
      float c0 = (na*nbv > 0.6f) ? 0.5f*(a+b) : 0.f;
      float c1 = (na*nc  > 0.6f) ? 0.5f*(a+c) : 0.f;
      float c2 = (nbv*nc > 0.6f) ? 0.5f*(b+c) : 0.f;
      float sc = c0*w0 + c1*w1 + c2*w2;
      float cf = has ? sc : (a+b+c)*(1.f/3.f);
      float wv = a*fw0 + b*fw1 + c*fw2;
      oc[j] = f2b(cf); ow[j] = f2b(wv);
    }
    int idx = (l5>>3)*4096 + rloc*64 + (((l5&7)*8) ^ ((rloc&7)<<3));
    *(u16x8*)&cw[idx] = oc;
    *(u16x8*)&ww[idx] = ow;
  }
  __syncthreads();

  // ---- gate GEMM: ga = common @ WtE^T ; K=256, B direct from L2 ----
  f32x4 ga[2][4];
  #pragma unroll
  for(int i=0;i<2;++i)
    #pragma unroll
    for(int j=0;j<4;++j) ga[i][j] = (f32x4){0.f,0.f,0.f,0.f};

  for(int kkg=0; kkg<256; kkg+=32){
    const int c = kkg >> 6, kk = kkg & 63;
    bf16x8 af[2], bq[4];
    #pragma unroll
    for(int i=0;i<2;++i)
      af[i] = *(const bf16x8*)&cw[c*4096 + (wr+i*16+lr)*64 + ((kk + quad*8) ^ swz)];
    #pragma unroll
    for(int j=0;j<4;++j)
      bq[j] = *(const bf16x8*)&WtE[(size_t)(wc+j*16+lr)*256 + kkg + quad*8];
    #pragma unroll
    for(int i=0;i<2;++i)
      #pragma unroll
      for(int j=0;j<4;++j)
        ga[i][j] = __builtin_amdgcn_mfma_f32_16x16x32_bf16(af[i], bq[j], ga[i][j], 0, 0, 0);
  }
  __syncthreads();   // all cw reads done

  // gate epilogue: ce = common * sigmoid(ga + be), in-place over cw (each elem 1 owner)
  #pragma unroll
  for(int j=0;j<4;++j){
    int col = wc + j*16 + lr;
    float bev = be[col];
    int within = j*16 + lr;
    #pragma unroll
    for(int i=0;i<2;++i){
      #pragma unroll
      for(int r=0;r<4;++r){
        int rl = wr + i*16 + quad*4 + r;
        int idx = (w & 3)*4096 + rl*64 + (within ^ ((rl&7)<<3));
        float cv = b2f(cw[idx]);
        float v = ga[i][j][r] + bev;
        cw[idx] = f2b(cv * __builtin_amdgcn_rcpf(1.f + __expf(-v)));
      }
    }
  }
  __syncthreads();   // ce visible

  // ---- final GEMM: fa = [weighted | ce] @ WtF^T ; K=512, B direct from L2 ----
  f32x4 fa[2][4];
  #pragma unroll
  for(int i=0;i<2;++i)
    #pragma unroll
    for(int j=0;j<4;++j) fa[i][j] = (f32x4){0.f,0.f,0.f,0.f};

  for(int kkg=0; kkg<512; kkg+=32){
    const int t = kkg >> 6, kk = kkg & 63;
    const u16* Asc = (t < 4) ? (ww + t*4096) : (cw + (t-4)*4096);
    bf16x8 af[2], bq[4];
    #pragma unroll
    for(int i=0;i<2;++i)
      af[i] = *(const bf16x8*)&Asc[(wr+i*16+lr)*64 + ((kk + quad*8) ^ swz)];
    #pragma unroll
    for(int j=0;j<4;++j)
      bq[j] = *(const bf16x8*)&WtF[(size_t)(wc+j*16+lr)*512 + kkg + quad*8];
    #pragma unroll
    for(int i=0;i<2;++i)
      #pragma unroll
      for(int j=0;j<4;++j)
        fa[i][j] = __builtin_amdgcn_mfma_f32_16x16x32_bf16(af[i], bq[j], fa[i][j], 0, 0, 0);
  }

  // final epilogue: fp32 stores; 16 lanes x 4B = full 64B segments per row
  #pragma unroll
  for(int j=0;j<4;++j){
    int col = wc + j*16 + lr;
    float bfc = bfv[col];
    #pragma unroll
    for(int i=0;i<2;++i){
      #pragma unroll
      for(int r=0;r<4;++r){
        size_t row = m0 + wr + i*16 + quad*4 + r;
        out[row*256 + col] = fa[i][j][r] + bfc;
      }
    }
  }
}

extern "C" void kernel_launch(void* const* d_in, const int* in_sizes, int n_in,
                              void* d_out, int out_size, void* d_ws, size_t ws_size,
                              hipStream_t stream) {
  const float* brics = (const float*)d_in[0];
  const float* fg    = (const float*)d_in[1];
  const float* ph    = (const float*)d_in[2];
  const float* W1[3] = {(const float*)d_in[3], (const float*)d_in[7], (const float*)d_in[11]};
  const float* b1[3] = {(const float*)d_in[4], (const float*)d_in[8], (const float*)d_in[12]};
  const float* W2[3] = {(const float*)d_in[5], (const float*)d_in[9], (const float*)d_in[13]};
  const float* b2[3] = {(const float*)d_in[6], (const float*)d_in[10], (const float*)d_in[14]};
  const float* Wg = (const float*)d_in[15];
  const float* bg = (const float*)d_in[16];
  const float* We = (const float*)d_in[17];
  const float* be = (const float*)d_in[18];
  const float* Wf = (const float*)d_in[19];
  const float* bf = (const float*)d_in[20];
  float* out = (float*)d_out;

  const int M = in_sizes[0] / 256;   // 65536

  // ---- workspace carve ----
  char* wsp = (char*)d_ws;
  size_t off = 0;
  auto carve = [&](size_t elems)->u16* {
    u16* p = (u16*)(wsp + off);
    off += ((elems*sizeof(u16)) + 255) & ~(size_t)255;
    return p;
  };
  u16* xb0 = carve((size_t)M*256);   // enc0 (brics)
  u16* xb1 = carve((size_t)M*256);   // enc1 (fg)
  u16* xb2 = carve((size_t)M*256);   // enc2 (ph)
  u16* Wt1[3], *Wt2[3];
  for(int i=0;i<3;++i) Wt1[i] = carve(320*256);
  for(int i=0;i<3;++i) Wt2[i] = carve(256*320);
  u16* WtE = carve(256*256);
  u16* WtF = carve(256*512);         // fused-output weight: [n=256][k=512]
  (void)n_in; (void)out_size; (void)ws_size;

  // ---- 1. transpose/convert all weights ----
  TArgs ta;
  for(int i=0;i<3;++i){
    ta.p[i]   = {W1[i], Wt1[i], 256, 300, 256, 320};  // Wt1: [320][256]
    ta.p[3+i] = {W2[i], Wt2[i], 300, 256, 320, 256};  // Wt2: [256][320]
  }
  ta.p[6] = {We, WtE, 256, 256, 256, 256};
  ta.p[7] = {Wf, WtF, 512, 256, 512, 256};            // Wf: [512,256] -> WtF [256][512]
  transpose_all<<<dim3(512, 8), 256, 0, stream>>>(ta);

  // ---- 2. fused encoders: enc_i = relu(x_i@W1+b1)@W2 + b2 (h never leaves LDS) ----
  EP ep_{};
  const float* xin[3] = {brics, fg, ph};
  u16* encp[3] = {xb0, xb1, xb2};
  for(int i=0;i<3;++i){
    ep_.X[i]=xin[i]; ep_.W1[i]=Wt1[i]; ep_.B1[i]=b1[i];
    ep_.W2[i]=Wt2[i]; ep_.B2[i]=b2[i]; ep_.E[i]=encp[i];
  }
  enc_k<<<dim3(M/64, 1, 3), 256, 0, stream>>>(ep_);

  // ---- 3. fused tail: mid + gate + final -> out ----
  fuse3_k<<<M/64, 512, 0, stream>>>(xb0, xb1, xb2, Wg, bg, WtE, be, WtF, bf, out);
}